// Round 18
// baseline (99.223 us; speedup 1.0000x reference)
//
#include <hip/hip_runtime.h>
#include <hip/hip_bf16.h>
#include <math.h>

#define NB 2
#define C 256
#define P 4096   // 64*64
#define EPS_F 1e-5f

typedef __attribute__((ext_vector_type(8))) short short8;
typedef __attribute__((ext_vector_type(4))) float f32x4;

__device__ __forceinline__ float bf2f(unsigned short u) {
    union { unsigned int i; float f; } x;
    x.i = ((unsigned int)u) << 16;
    return x.f;
}

// ---------------- K1: per-channel mean of featureT over n,h,w ----------------
__global__ void k_mean(const float* __restrict__ fT, float* __restrict__ mean) {
    int c = blockIdx.x;
    int t = threadIdx.x;
    const float* p0 = fT + (size_t)c * P;          // n=0
    const float* p1 = fT + (size_t)(C + c) * P;    // n=1
    float s = 0.f;
    for (int i = t; i < P; i += 256) s += p0[i] + p1[i];
    __shared__ float red[256];
    red[t] = s; __syncthreads();
    for (int o = 128; o > 0; o >>= 1) { if (t < o) red[t] += red[t + o]; __syncthreads(); }
    if (t == 0) mean[c] = red[0] * (1.f / 8192.f);
}

// ---------------- K2: fused center + L2-norm + transpose-pack to bf16 (both inputs) ----------------
__global__ __launch_bounds__(256) void k_normpack(const float* __restrict__ fI,
                                                  const float* __restrict__ fT,
                                                  const float* __restrict__ mean,
                                                  __hip_bfloat16* __restrict__ TI,
                                                  __hip_bfloat16* __restrict__ TT) {
    // grid: x = p-tile(128 tiles of 32 pixels), y = n(2), z = which input (2)
    __shared__ float mn[C];
    __shared__ float tile[C][33];
    __shared__ float part[8][32];
    __shared__ float srn[32];
    int t = threadIdx.x;
    const float* f = blockIdx.z ? fT : fI;
    __hip_bfloat16* out = blockIdx.z ? TT : TI;
    mn[t] = mean[t];
    __syncthreads();
    int n = blockIdx.y, p0 = blockIdx.x * 32;
    int pl = t & 31, cg = t >> 5;
    const float* base = f + (size_t)n * C * P + p0 + pl;
    float acc = 0.f;
    #pragma unroll 4
    for (int cc = 0; cc < 32; cc++) {
        int c = cg * 32 + cc;
        float v = base[(size_t)c * P] - mn[c];
        tile[c][pl] = v;
        acc += v * v;
    }
    part[cg][pl] = acc;
    __syncthreads();
    if (t < 32) {
        float s = 0.f;
        #pragma unroll
        for (int g = 0; g < 8; g++) s += part[g][t];
        srn[t] = rsqrtf(s);
    }
    __syncthreads();
    #pragma unroll
    for (int it = 0; it < 4; it++) {
        int flat = it * 2048 + t * 8;
        int p = flat >> 8;          // 0..31
        int c = flat & 255;
        float rn = srn[p];
        union { __hip_bfloat16 h[8]; short8 s; } u;
        #pragma unroll
        for (int k = 0; k < 8; k++)
            u.h[k] = __float2bfloat16(tile[c + k][p] * rn);
        *(short8*)(out + ((size_t)(n * P + p0 + p)) * C + c) = u.s;
    }
}

// ---------------- staging: 4 waves stage a 128-row x 32-col (64B/row) panel ----------------
__device__ __forceinline__ void stage_tile(const __hip_bfloat16* __restrict__ gbase,
                                           __hip_bfloat16* lbuf, int kk, int wid, int lane) {
    #pragma unroll
    for (int j = 0; j < 2; j++) {
        int row = wid * 32 + j * 16 + (lane >> 2);
        int cb = (lane & 3) * 16;
        int scb = cb ^ (((row >> 1) & 3) << 4);
        const char* gp = (const char*)gbase + (size_t)row * (C * 2) + kk * 64 + scb;
        char* lp = (char*)lbuf + (wid * 32 + j * 16) * 64;   // wave-uniform base
        __builtin_amdgcn_global_load_lds(
            (const __attribute__((address_space(1))) void*)gp,
            (__attribute__((address_space(3))) void*)lp, 16, 0, 0);
    }
}

__device__ __forceinline__ short8 ldfrag(const __hip_bfloat16* lbuf, int rloc, int kb) {
    int addr = rloc * 64 + (kb ^ (((rloc >> 1) & 3) << 4));
    return *(const short8*)((const char*)lbuf + addr);
}

// ---------------- K4: fused GEMM: 2 q-tiles/block share B staging; depth-2 prefetch, counted vmcnt ----------------
__global__ __launch_bounds__(256) void k_gemm(const __hip_bfloat16* __restrict__ TI,
                                              const __hip_bfloat16* __restrict__ TT,
                                              __hip_bfloat16* __restrict__ D,
                                              float* __restrict__ Mpart) {
    // grid: x = p-tile(32), y = q-pair(16), z = n(2); 4 waves 2x2 over 2x(128x128), BK=32
    // LDS: 3 bufs x 24 KB; per buf: A0 at +0, A1 at +8K, B at +16K. Reused as transpose buf.
    __shared__ char smem[73728];
    int lane = threadIdx.x & 63, wid = threadIdx.x >> 6;
    int wr = wid >> 1, wc = wid & 1;
    int n = blockIdx.z;
    const __hip_bfloat16* A0 = TI + ((size_t)n * P + blockIdx.y * 256) * C;
    const __hip_bfloat16* A1 = A0 + (size_t)128 * C;
    const __hip_bfloat16* B  = TT + ((size_t)n * P + blockIdx.x * 128) * C;

    f32x4 acc[2][4][4];
    #pragma unroll
    for (int qt = 0; qt < 2; qt++)
        #pragma unroll
        for (int m = 0; m < 4; m++)
            #pragma unroll
            for (int nt = 0; nt < 4; nt++)
                acc[qt][m][nt] = (f32x4){0.f, 0.f, 0.f, 0.f};

    int rA = lane & 15;
    int kb = (lane >> 4) * 16;

    // prologue: stage k0, k1 (12 loads/lane in flight)
    stage_tile(A0, (__hip_bfloat16*)(smem), 0, wid, lane);
    stage_tile(A1, (__hip_bfloat16*)(smem + 8192), 0, wid, lane);
    stage_tile(B,  (__hip_bfloat16*)(smem + 16384), 0, wid, lane);
    stage_tile(A0, (__hip_bfloat16*)(smem + 24576), 1, wid, lane);
    stage_tile(A1, (__hip_bfloat16*)(smem + 24576 + 8192), 1, wid, lane);
    stage_tile(B,  (__hip_bfloat16*)(smem + 24576 + 16384), 1, wid, lane);
    asm volatile("s_waitcnt vmcnt(6)" ::: "memory");   // k0's 6 loads done; k1's in flight
    __builtin_amdgcn_s_barrier();
    __builtin_amdgcn_sched_barrier(0);

    #pragma unroll
    for (int t = 0; t < 8; t++) {
        int cur = t % 3;
        if (t < 6) {
            int nxt = (t + 2) % 3;
            char* nb = smem + nxt * 24576;
            stage_tile(A0, (__hip_bfloat16*)(nb), t + 2, wid, lane);
            stage_tile(A1, (__hip_bfloat16*)(nb + 8192), t + 2, wid, lane);
            stage_tile(B,  (__hip_bfloat16*)(nb + 16384), t + 2, wid, lane);
        }
        char* cb = smem + cur * 24576;
        short8 b[4];
        #pragma unroll
        for (int nt = 0; nt < 4; nt++)
            b[nt] = ldfrag((__hip_bfloat16*)(cb + 16384), wc * 64 + nt * 16 + rA, kb);
        #pragma unroll
        for (int qt = 0; qt < 2; qt++) {
            short8 a[4];
            #pragma unroll
            for (int m = 0; m < 4; m++)
                a[m] = ldfrag((__hip_bfloat16*)(cb + qt * 8192), wr * 64 + m * 16 + rA, kb);
            #pragma unroll
            for (int m = 0; m < 4; m++)
                #pragma unroll
                for (int nt = 0; nt < 4; nt++)
                    acc[qt][m][nt] = __builtin_amdgcn_mfma_f32_16x16x32_bf16(a[m], b[nt], acc[qt][m][nt], 0, 0, 0);
        }
        if (t < 6)       asm volatile("s_waitcnt vmcnt(6)" ::: "memory");
        else if (t == 6) asm volatile("s_waitcnt vmcnt(0)" ::: "memory");
        __builtin_amdgcn_s_barrier();
        __builtin_amdgcn_sched_barrier(0);
    }

    // epilogue 1: per q-tile: acc -> swizzled LDS transpose, then 256B-segment coalesced stores
    int rj = (lane >> 4) * 4, cl = lane & 15;
    char* tb = smem;   // 128 rows x 256 B = 32 KB
    int pb0 = blockIdx.x * 128;
    char* Dn = (char*)(D + (size_t)n * P * P);
    #pragma unroll
    for (int qt = 0; qt < 2; qt++) {
        #pragma unroll
        for (int m = 0; m < 4; m++)
            #pragma unroll
            for (int nt = 0; nt < 4; nt++)
                #pragma unroll
                for (int j = 0; j < 4; j++) {
                    int row = wr * 64 + m * 16 + rj + j;
                    int colb = (wc * 64 + nt * 16 + cl) * 2;
                    *(__hip_bfloat16*)(tb + row * 256 + (colb ^ (((row >> 2) & 3) << 5))) =
                        __float2bfloat16(acc[qt][m][nt][j]);
                }
        __syncthreads();
        int qb0 = blockIdx.y * 256 + qt * 128;
        #pragma unroll
        for (int rb = 0; rb < 8; rb++) {
            int row = wid * 32 + rb * 4 + (lane >> 4);
            int sb = cl * 16;
            short8 v = *(const short8*)(tb + row * 256 + (sb ^ (((row >> 2) & 3) << 5)));
            *(short8*)(Dn + ((size_t)(qb0 + row) * P + pb0) * 2 + sb) = v;
        }
        __syncthreads();   // tb reads done before next qt overwrites
    }

    // epilogue 2: row-max partials (exact, fp32)
    int pt = blockIdx.x * 2 + wc;
    #pragma unroll
    for (int qt = 0; qt < 2; qt++) {
        int qb = blockIdx.y * 256 + qt * 128 + wr * 64;
        #pragma unroll
        for (int m = 0; m < 4; m++) {
            f32x4 mx = acc[qt][m][0];
            #pragma unroll
            for (int nt = 1; nt < 4; nt++)
                #pragma unroll
                for (int j = 0; j < 4; j++)
                    mx[j] = fmaxf(mx[j], acc[qt][m][nt][j]);
            #pragma unroll
            for (int j = 0; j < 4; j++)
                #pragma unroll
                for (int o = 1; o < 16; o <<= 1)
                    mx[j] = fmaxf(mx[j], __shfl_xor(mx[j], o));
            if ((lane & 15) == 0) {
                int qbase = qb + m * 16 + (lane >> 4) * 4;
                #pragma unroll
                for (int j = 0; j < 4; j++)
                    Mpart[((size_t)(n * P + qbase + j)) * 64 + pt] = mx[j];
            }
        }
    }
}

// ---------------- K5: fused row-stats + log-domain colmax, LDS-free (L2-hot re-read) ----------------
__global__ __launch_bounds__(512) void k_zcol(const __hip_bfloat16* __restrict__ D,
                                              const float* __restrict__ Mpart,
                                              float* __restrict__ Cpart) {
    // grid: x = row-group (256 groups of 16 rows), y = n(2); 512 threads, ~64 B LDS
    __shared__ float st2[8], sc[8];
    int t = threadIdx.x, lane = t & 63, wv = t >> 6;
    int n = blockIdx.y, g = blockIdx.x;

    float cm[8];
    #pragma unroll
    for (int j = 0; j < 8; j++) cm[j] = -1e30f;

    #pragma unroll
    for (int s = 0; s < 2; s++) {
        int q = g * 16 + s * 8 + wv;
        size_t row = (size_t)n * P + q;
        // row max from gemm partials
        float m = Mpart[row * 64 + lane];
        #pragma unroll
        for (int o = 32; o > 0; o >>= 1) m = fmaxf(m, __shfl_xor(m, o));
        float t2 = 5.f / ((1.f - m) * 0.5f + EPS_F);

        // Z: wave reads its own row directly (coalesced 16B/lane)
        const short8* src = (const short8*)(D + row * P);
        float z = 0.f;
        #pragma unroll
        for (int k = 0; k < 8; k++) {
            short8 v = src[k * 64 + lane];
            #pragma unroll
            for (int j = 0; j < 8; j++)
                z += __expf(t2 * (bf2f((unsigned short)v[j]) - m));
        }
        #pragma unroll
        for (int o = 32; o > 0; o >>= 1) z += __shfl_xor(z, o);
        if (lane == 0) { st2[wv] = t2; sc[wv] = -t2 * m - logf(z); }
        __syncthreads();

        // colmax: thread t owns cols t*8..t*8+7; rows are L2-hot from the Z pass
        const __hip_bfloat16* Db = D + ((size_t)n * P + g * 16 + s * 8) * P;
        #pragma unroll
        for (int r = 0; r < 8; r++) {
            short8 v = *(const short8*)(Db + (size_t)r * P + t * 8);
            float tt = st2[r], cc = sc[r];
            #pragma unroll
            for (int j = 0; j < 8; j++)
                cm[j] = fmaxf(cm[j], fmaf(tt, bf2f((unsigned short)v[j]), cc));
        }
        __syncthreads();   // st2/sc reused next stage
    }

    float* cp = Cpart + ((size_t)(n * 256 + g)) * P + t * 8;
    f32x4 v0 = {cm[0], cm[1], cm[2], cm[3]};
    f32x4 v1 = {cm[4], cm[5], cm[6], cm[7]};
    *(f32x4*)cp = v0;
    *(f32x4*)(cp + 4) = v1;
}

// ---------------- colred stage 1: reduce 256 groups -> 8 partials ----------------
__global__ void k_colred1(const float* __restrict__ Cpart, float* __restrict__ Cred2) {
    // grid: x(32) covers np, y(8) covers g-chunks of 32
    int np = blockIdx.x * 256 + threadIdx.x;  // flat n*P+p
    int n = np >> 12, p = np & 4095;
    const float* base = Cpart + (size_t)(n * 256) * P + p;
    float c = -1e30f;
    int g0 = blockIdx.y * 32;
    #pragma unroll 8
    for (int g = 0; g < 32; g++)
        c = fmaxf(c, base[(size_t)(g0 + g) * P]);
    Cred2[blockIdx.y * 8192 + np] = c;
}

// ---------------- colred stage 2: reduce 8 partials, exp back from log-domain ----------------
__global__ void k_colred2(const float* __restrict__ Cred2, float* __restrict__ colmax) {
    int np = blockIdx.x * 256 + threadIdx.x;
    float c = -1e30f;
    #pragma unroll
    for (int y = 0; y < 8; y++)
        c = fmaxf(c, Cred2[y * 8192 + np]);
    colmax[np] = __expf(c);
}

// ---------------- final: -log(mean_p colmax), mean over n ----------------
__global__ void k_final(const float* __restrict__ colmax, float* __restrict__ out) {
    __shared__ float red[256];
    int t = threadIdx.x;
    float cx[NB];
    for (int n = 0; n < NB; n++) {
        float s = 0.f;
        for (int i = t; i < P; i += 256) s += colmax[n * P + i];
        red[t] = s; __syncthreads();
        for (int o = 128; o > 0; o >>= 1) { if (t < o) red[t] += red[t + o]; __syncthreads(); }
        cx[n] = -logf(red[0] * (1.f / (float)P));
        __syncthreads();
    }
    if (t == 0) out[0] = 0.5f * (cx[0] + cx[1]);
}

extern "C" void kernel_launch(void* const* d_in, const int* in_sizes, int n_in,
                              void* d_out, int out_size, void* d_ws, size_t ws_size,
                              hipStream_t stream) {
    const float* fT = (const float*)d_in[0];   // featureT
    const float* fI = (const float*)d_in[1];   // featureI
    float* out = (float*)d_out;

    char* ws = (char*)d_ws;
    size_t off = 0;
    __hip_bfloat16* TI = (__hip_bfloat16*)(ws + off); off += 4194304;
    __hip_bfloat16* TT = (__hip_bfloat16*)(ws + off); off += 4194304;
    __hip_bfloat16* D  = (__hip_bfloat16*)(ws + off); off += (size_t)NB * P * P * 2;  // 67 MiB
    float* Mpart  = (float*)(ws + off); off += (size_t)NB * P * 64 * 4;               // 2 MiB
    float* Cpart  = (float*)(ws + off); off += (size_t)NB * 256 * P * 4;              // 8 MiB
    float* Cred2  = (float*)(ws + off); off += (size_t)8 * NB * P * 4;                // 256 KiB
    float* mean   = (float*)(ws + off); off += 1024;
    float* colmax = (float*)(ws + off); off += 32768;

    k_mean<<<256, 256, 0, stream>>>(fT, mean);
    k_normpack<<<dim3(128, 2, 2), 256, 0, stream>>>(fI, fT, mean, TI, TT);
    k_gemm<<<dim3(32, 16, 2), 256, 0, stream>>>(TI, TT, D, Mpart);
    k_zcol<<<dim3(256, 2), 512, 0, stream>>>(D, Mpart, Cpart);
    k_colred1<<<dim3(32, 8), 256, 0, stream>>>(Cpart, Cred2);
    k_colred2<<<32, 256, 0, stream>>>(Cred2, colmax);
    k_final<<<1, 256, 0, stream>>>(colmax, out);
}

// Round 19
// 85.687 us; speedup vs baseline: 1.1580x; 1.1580x over previous
//
#include <hip/hip_runtime.h>
#include <hip/hip_bf16.h>
#include <math.h>

#define NB 2
#define C 256
#define P 4096   // 64*64
#define EPS_F 1e-5f

typedef __attribute__((ext_vector_type(8))) short short8;
typedef __attribute__((ext_vector_type(4))) float f32x4;

__device__ __forceinline__ float bf2f(unsigned short u) {
    union { unsigned int i; float f; } x;
    x.i = ((unsigned int)u) << 16;
    return x.f;
}

// ---------------- K1: per-channel mean of featureT over n,h,w ----------------
__global__ void k_mean(const float* __restrict__ fT, float* __restrict__ mean) {
    int c = blockIdx.x;
    int t = threadIdx.x;
    const float* p0 = fT + (size_t)c * P;          // n=0
    const float* p1 = fT + (size_t)(C + c) * P;    // n=1
    float s = 0.f;
    for (int i = t; i < P; i += 256) s += p0[i] + p1[i];
    __shared__ float red[256];
    red[t] = s; __syncthreads();
    for (int o = 128; o > 0; o >>= 1) { if (t < o) red[t] += red[t + o]; __syncthreads(); }
    if (t == 0) mean[c] = red[0] * (1.f / 8192.f);
}

// ---------------- K2: fused center + L2-norm + transpose-pack to bf16 (both inputs) ----------------
__global__ __launch_bounds__(256) void k_normpack(const float* __restrict__ fI,
                                                  const float* __restrict__ fT,
                                                  const float* __restrict__ mean,
                                                  __hip_bfloat16* __restrict__ TI,
                                                  __hip_bfloat16* __restrict__ TT) {
    // grid: x = p-tile(128 tiles of 32 pixels), y = n(2), z = which input (2)
    __shared__ float mn[C];
    __shared__ float tile[C][33];
    __shared__ float part[8][32];
    __shared__ float srn[32];
    int t = threadIdx.x;
    const float* f = blockIdx.z ? fT : fI;
    __hip_bfloat16* out = blockIdx.z ? TT : TI;
    mn[t] = mean[t];
    __syncthreads();
    int n = blockIdx.y, p0 = blockIdx.x * 32;
    int pl = t & 31, cg = t >> 5;
    const float* base = f + (size_t)n * C * P + p0 + pl;
    float acc = 0.f;
    #pragma unroll 4
    for (int cc = 0; cc < 32; cc++) {
        int c = cg * 32 + cc;
        float v = base[(size_t)c * P] - mn[c];
        tile[c][pl] = v;
        acc += v * v;
    }
    part[cg][pl] = acc;
    __syncthreads();
    if (t < 32) {
        float s = 0.f;
        #pragma unroll
        for (int g = 0; g < 8; g++) s += part[g][t];
        srn[t] = rsqrtf(s);
    }
    __syncthreads();
    #pragma unroll
    for (int it = 0; it < 4; it++) {
        int flat = it * 2048 + t * 8;
        int p = flat >> 8;          // 0..31
        int c = flat & 255;
        float rn = srn[p];
        union { __hip_bfloat16 h[8]; short8 s; } u;
        #pragma unroll
        for (int k = 0; k < 8; k++)
            u.h[k] = __float2bfloat16(tile[c + k][p] * rn);
        *(short8*)(out + ((size_t)(n * P + p0 + p)) * C + c) = u.s;
    }
}

// ---------------- staging: one wave stages 32 rows x 32 cols (64B/row) of a tile ----------------
__device__ __forceinline__ void stage_tile(const __hip_bfloat16* __restrict__ gbase,
                                           __hip_bfloat16* lbuf, int kk, int wid, int lane) {
    #pragma unroll
    for (int j = 0; j < 2; j++) {
        int row = wid * 32 + j * 16 + (lane >> 2);
        int cb = (lane & 3) * 16;
        int scb = cb ^ (((row >> 1) & 3) << 4);
        const char* gp = (const char*)gbase + (size_t)row * (C * 2) + kk * 64 + scb;
        char* lp = (char*)lbuf + (wid * 32 + j * 16) * 64;   // wave-uniform base
        __builtin_amdgcn_global_load_lds(
            (const __attribute__((address_space(1))) void*)gp,
            (__attribute__((address_space(3))) void*)lp, 16, 0, 0);
    }
}

__device__ __forceinline__ short8 ldfrag(const __hip_bfloat16* lbuf, int rloc, int kb) {
    int addr = rloc * 64 + (kb ^ (((rloc >> 1) & 3) << 4));
    return *(const short8*)((const char*)lbuf + addr);
}

// ---------------- K4: fused GEMM (round-12 winner): depth-2 prefetch, counted vmcnt ----------------
__global__ __launch_bounds__(256) void k_gemm(const __hip_bfloat16* __restrict__ TI,
                                              const __hip_bfloat16* __restrict__ TT,
                                              __hip_bfloat16* __restrict__ D,
                                              float* __restrict__ Mpart) {
    // grid: x = p-tile(32), y = q-tile(32), z = n(2); 4 waves 2x2 over 128x128, BK=32
    __shared__ char smem[49152];
    int lane = threadIdx.x & 63, wid = threadIdx.x >> 6;
    int wr = wid >> 1, wc = wid & 1;
    int n = blockIdx.z;
    const __hip_bfloat16* A = TI + ((size_t)n * P + blockIdx.y * 128) * C;
    const __hip_bfloat16* B = TT + ((size_t)n * P + blockIdx.x * 128) * C;

    f32x4 acc[4][4];
    #pragma unroll
    for (int m = 0; m < 4; m++)
        #pragma unroll
        for (int nt = 0; nt < 4; nt++)
            acc[m][nt] = (f32x4){0.f, 0.f, 0.f, 0.f};

    int rA = lane & 15;
    int kb = (lane >> 4) * 16;

    // prologue: stage k0, k1 (8 loads/wave in flight)
    stage_tile(A, (__hip_bfloat16*)(smem), 0, wid, lane);
    stage_tile(B, (__hip_bfloat16*)(smem + 24576), 0, wid, lane);
    stage_tile(A, (__hip_bfloat16*)(smem + 8192), 1, wid, lane);
    stage_tile(B, (__hip_bfloat16*)(smem + 24576 + 8192), 1, wid, lane);
    asm volatile("s_waitcnt vmcnt(4)" ::: "memory");
    __builtin_amdgcn_s_barrier();
    __builtin_amdgcn_sched_barrier(0);

    #pragma unroll
    for (int t = 0; t < 8; t++) {
        int cur = t % 3;
        if (t < 6) {
            int nxt = (t + 2) % 3;
            stage_tile(A, (__hip_bfloat16*)(smem + nxt * 8192), t + 2, wid, lane);
            stage_tile(B, (__hip_bfloat16*)(smem + 24576 + nxt * 8192), t + 2, wid, lane);
        }
        __hip_bfloat16* lAc = (__hip_bfloat16*)(smem + cur * 8192);
        __hip_bfloat16* lBc = (__hip_bfloat16*)(smem + 24576 + cur * 8192);
        short8 a[4], b[4];
        #pragma unroll
        for (int m = 0; m < 4; m++)
            a[m] = ldfrag(lAc, wr * 64 + m * 16 + rA, kb);
        #pragma unroll
        for (int nt = 0; nt < 4; nt++)
            b[nt] = ldfrag(lBc, wc * 64 + nt * 16 + rA, kb);
        #pragma unroll
        for (int m = 0; m < 4; m++)
            #pragma unroll
            for (int nt = 0; nt < 4; nt++)
                acc[m][nt] = __builtin_amdgcn_mfma_f32_16x16x32_bf16(a[m], b[nt], acc[m][nt], 0, 0, 0);
        if (t < 6)       asm volatile("s_waitcnt vmcnt(4)" ::: "memory");
        else if (t == 6) asm volatile("s_waitcnt vmcnt(0)" ::: "memory");
        __builtin_amdgcn_s_barrier();
        __builtin_amdgcn_sched_barrier(0);
    }

    // epilogue 1: acc -> swizzled LDS transpose, then 256B-segment coalesced stores
    int rj = (lane >> 4) * 4, cl = lane & 15;
    {
        char* tb = smem;   // 128 rows x 256 B
        #pragma unroll
        for (int m = 0; m < 4; m++)
            #pragma unroll
            for (int nt = 0; nt < 4; nt++)
                #pragma unroll
                for (int j = 0; j < 4; j++) {
                    int row = wr * 64 + m * 16 + rj + j;
                    int colb = (wc * 64 + nt * 16 + cl) * 2;
                    *(__hip_bfloat16*)(tb + row * 256 + (colb ^ (((row >> 2) & 3) << 5))) =
                        __float2bfloat16(acc[m][nt][j]);
                }
        __syncthreads();
        int qb0 = blockIdx.y * 128, pb0 = blockIdx.x * 128;
        char* Dn = (char*)(D + (size_t)n * P * P);
        #pragma unroll
        for (int rb = 0; rb < 8; rb++) {
            int row = wid * 32 + rb * 4 + (lane >> 4);
            int sb = cl * 16;
            short8 v = *(const short8*)(tb + row * 256 + (sb ^ (((row >> 2) & 3) << 5)));
            *(short8*)(Dn + ((size_t)(qb0 + row) * P + pb0) * 2 + sb) = v;
        }
    }

    // epilogue 2: row-max partials (exact, fp32)
    int qb = blockIdx.y * 128 + wr * 64;
    int pt = blockIdx.x * 2 + wc;
    #pragma unroll
    for (int m = 0; m < 4; m++) {
        f32x4 mx = acc[m][0];
        #pragma unroll
        for (int nt = 1; nt < 4; nt++)
            #pragma unroll
            for (int j = 0; j < 4; j++)
                mx[j] = fmaxf(mx[j], acc[m][nt][j]);
        #pragma unroll
        for (int j = 0; j < 4; j++)
            #pragma unroll
            for (int o = 1; o < 16; o <<= 1)
                mx[j] = fmaxf(mx[j], __shfl_xor(mx[j], o));
        if ((lane & 15) == 0) {
            int qbase = qb + m * 16 + (lane >> 4) * 4;
            #pragma unroll
            for (int j = 0; j < 4; j++)
                Mpart[((size_t)(n * P + qbase + j)) * 64 + pt] = mx[j];
        }
    }
}

// ---------------- K5: fused row-stats + log-domain colmax; 16 rows/block in 2 LDS stages ----------------
__global__ __launch_bounds__(512) void k_zcol(const __hip_bfloat16* __restrict__ D,
                                              const float* __restrict__ Mpart,
                                              float* __restrict__ Cpart) {
    // grid: x = row-group (256 groups of 16 rows), y = n(2); 512 threads, 64 KB LDS
    __shared__ __hip_bfloat16 tile[8][P];   // 64 KB (one 8-row stage)
    __shared__ float st2[8], sc[8];
    int t = threadIdx.x, lane = t & 63, wv = t >> 6;
    int n = blockIdx.y, g = blockIdx.x;

    float cm[8];
    #pragma unroll
    for (int j = 0; j < 8; j++) cm[j] = -1e30f;

    #pragma unroll
    for (int s = 0; s < 2; s++) {
        int q = g * 16 + s * 8 + wv;
        size_t row = (size_t)n * P + q;
        // stage own row (8 KB) linearly into LDS
        const char* gsrc = (const char*)(D + row * P);
        char* ldst = (char*)&tile[wv][0];
        #pragma unroll
        for (int i = 0; i < 8; i++)
            __builtin_amdgcn_global_load_lds(
                (const __attribute__((address_space(1))) void*)(gsrc + i * 1024 + lane * 16),
                (__attribute__((address_space(3))) void*)(ldst + i * 1024), 16, 0, 0);

        // row max from gemm partials
        float m = Mpart[row * 64 + lane];
        #pragma unroll
        for (int o = 32; o > 0; o >>= 1) m = fmaxf(m, __shfl_xor(m, o));
        float t2 = 5.f / ((1.f - m) * 0.5f + EPS_F);

        __syncthreads();   // staging complete

        // Z: wave reduces its own row from LDS
        const short8* trow = (const short8*)&tile[wv][0];
        float z = 0.f;
        #pragma unroll
        for (int k = 0; k < 8; k++) {
            short8 v = trow[k * 64 + lane];
            #pragma unroll
            for (int j = 0; j < 8; j++)
                z += __expf(t2 * (bf2f((unsigned short)v[j]) - m));
        }
        #pragma unroll
        for (int o = 32; o > 0; o >>= 1) z += __shfl_xor(z, o);
        if (lane == 0) { st2[wv] = t2; sc[wv] = -t2 * m - logf(z); }
        __syncthreads();

        // colmax: thread t owns cols t*8..t*8+7, accumulates over the 8 staged rows
        #pragma unroll
        for (int r = 0; r < 8; r++) {
            short8 v = *(const short8*)&tile[r][t * 8];
            float tt = st2[r], cc = sc[r];
            #pragma unroll
            for (int j = 0; j < 8; j++)
                cm[j] = fmaxf(cm[j], fmaf(tt, bf2f((unsigned short)v[j]), cc));
        }
        __syncthreads();   // colmax reads done before next stage overwrites tile
    }

    float* cp = Cpart + ((size_t)(n * 256 + g)) * P + t * 8;
    f32x4 v0 = {cm[0], cm[1], cm[2], cm[3]};
    f32x4 v1 = {cm[4], cm[5], cm[6], cm[7]};
    *(f32x4*)cp = v0;
    *(f32x4*)(cp + 4) = v1;
}

// ---------------- colred stage 1: reduce 256 groups -> 8 partials ----------------
__global__ void k_colred1(const float* __restrict__ Cpart, float* __restrict__ Cred2) {
    // grid: x(32) covers np, y(8) covers g-chunks of 32
    int np = blockIdx.x * 256 + threadIdx.x;  // flat n*P+p
    int n = np >> 12, p = np & 4095;
    const float* base = Cpart + (size_t)(n * 256) * P + p;
    float c = -1e30f;
    int g0 = blockIdx.y * 32;
    #pragma unroll 8
    for (int g = 0; g < 32; g++)
        c = fmaxf(c, base[(size_t)(g0 + g) * P]);
    Cred2[blockIdx.y * 8192 + np] = c;
}

// ---------------- colred stage 2: reduce 8 partials, exp back from log-domain ----------------
__global__ void k_colred2(const float* __restrict__ Cred2, float* __restrict__ colmax) {
    int np = blockIdx.x * 256 + threadIdx.x;
    float c = -1e30f;
    #pragma unroll
    for (int y = 0; y < 8; y++)
        c = fmaxf(c, Cred2[y * 8192 + np]);
    colmax[np] = __expf(c);
}

// ---------------- final: -log(mean_p colmax), mean over n ----------------
__global__ void k_final(const float* __restrict__ colmax, float* __restrict__ out) {
    __shared__ float red[256];
    int t = threadIdx.x;
    float cx[NB];
    for (int n = 0; n < NB; n++) {
        float s = 0.f;
        for (int i = t; i < P; i += 256) s += colmax[n * P + i];
        red[t] = s; __syncthreads();
        for (int o = 128; o > 0; o >>= 1) { if (t < o) red[t] += red[t + o]; __syncthreads(); }
        cx[n] = -logf(red[0] * (1.f / (float)P));
        __syncthreads();
    }
    if (t == 0) out[0] = 0.5f * (cx[0] + cx[1]);
}

extern "C" void kernel_launch(void* const* d_in, const int* in_sizes, int n_in,
                              void* d_out, int out_size, void* d_ws, size_t ws_size,
                              hipStream_t stream) {
    const float* fT = (const float*)d_in[0];   // featureT
    const float* fI = (const float*)d_in[1];   // featureI
    float* out = (float*)d_out;

    char* ws = (char*)d_ws;
    size_t off = 0;
    __hip_bfloat16* TI = (__hip_bfloat16*)(ws + off); off += 4194304;
    __hip_bfloat16* TT = (__hip_bfloat16*)(ws + off); off += 4194304;
    __hip_bfloat16* D  = (__hip_bfloat16*)(ws + off); off += (size_t)NB * P * P * 2;  // 67 MiB
    float* Mpart  = (float*)(ws + off); off += (size_t)NB * P * 64 * 4;               // 2 MiB
    float* Cpart  = (float*)(ws + off); off += (size_t)NB * 256 * P * 4;              // 8 MiB
    float* Cred2  = (float*)(ws + off); off += (size_t)8 * NB * P * 4;                // 256 KiB
    float* mean   = (float*)(ws + off); off += 1024;
    float* colmax = (float*)(ws + off); off += 32768;

    k_mean<<<256, 256, 0, stream>>>(fT, mean);
    k_normpack<<<dim3(128, 2, 2), 256, 0, stream>>>(fI, fT, mean, TI, TT);
    k_gemm<<<dim3(32, 32, 2), 256, 0, stream>>>(TI, TT, D, Mpart);
    k_zcol<<<dim3(256, 2), 512, 0, stream>>>(D, Mpart, Cpart);
    k_colred1<<<dim3(32, 8), 256, 0, stream>>>(Cpart, Cred2);
    k_colred2<<<32, 256, 0, stream>>>(Cred2, colmax);
    k_final<<<1, 256, 0, stream>>>(colmax, out);
}